// Round 1
// baseline (541.465 us; speedup 1.0000x reference)
//
#include <hip/hip_runtime.h>
#include <hip/hip_bf16.h>

#define NFEAT 128
#define ALPHA 0.2f

// ---------------- CSR build ----------------

__global__ __launch_bounds__(256) void k_zero2(int* __restrict__ a, int* __restrict__ b, int n) {
  int i = blockIdx.x * 256 + threadIdx.x;
  if (i < n) { a[i] = 0; b[i] = 0; }
}

__global__ __launch_bounds__(256) void k_hist(const int* __restrict__ dst, int* __restrict__ cnt, int E) {
  int e = blockIdx.x * 256 + threadIdx.x;
  if (e < E) atomicAdd(&cnt[dst[e]], 1);
}

__global__ __launch_bounds__(256) void k_dis(const int* __restrict__ cnt, float* __restrict__ dis, int n) {
  int i = blockIdx.x * 256 + threadIdx.x;
  if (i < n) dis[i] = rsqrtf((float)(cnt[i] + 1));  // +1 self-loop; deg>0 always
}

// single-block exclusive scan of cnt[0..n) -> rowptr[0..n]
__global__ __launch_bounds__(1024) void k_scan(const int* __restrict__ cnt, int* __restrict__ rowptr, int n) {
  __shared__ int sums[1024];
  int t = threadIdx.x;
  int chunk = (n + 1023) >> 10;
  int lo = t * chunk;
  int hi = lo + chunk; if (hi > n) hi = n;
  int s = 0;
  for (int i = lo; i < hi; ++i) s += cnt[i];
  sums[t] = s;
  __syncthreads();
  for (int off = 1; off < 1024; off <<= 1) {
    int v = (t >= off) ? sums[t - off] : 0;
    __syncthreads();
    sums[t] += v;
    __syncthreads();
  }
  int run = (t == 0) ? 0 : sums[t - 1];
  for (int i = lo; i < hi; ++i) { rowptr[i] = run; run += cnt[i]; }
  if (t == 1023) rowptr[n] = run;
}

__global__ __launch_bounds__(256) void k_fill(const int* __restrict__ src, const int* __restrict__ dst,
    const int* __restrict__ rowptr, int* __restrict__ fill, int* __restrict__ lst, int E) {
  int e = blockIdx.x * 256 + threadIdx.x;
  if (e < E) {
    int d = dst[e];
    int p = rowptr[d] + atomicAdd(&fill[d], 1);
    lst[p] = src[e];
  }
}

// ---------------- skinny GEMMs (W in LDS, thread = 1 row x 16 outs) ----------------

template<int K, int OW, bool HAS_BIAS, bool LEAKY, bool SCALE>
__global__ __launch_bounds__(256) void k_gemm(const float* __restrict__ A,
    const float* __restrict__ W, const float* __restrict__ bias,
    const float* __restrict__ dis, float* __restrict__ out, int n) {
  constexpr int TPR = OW / 16;       // threads per row
  constexpr int RPB = 256 / TPR;     // rows per block
  __shared__ float sW[K * OW];
  int t = threadIdx.x;
  {
    constexpr int NV = (K * OW) / (4 * 256);
    const float4* W4 = (const float4*)W;
    float4* s4 = (float4*)sW;
    #pragma unroll
    for (int i = 0; i < NV; ++i) s4[t + i * 256] = W4[t + i * 256];
  }
  __syncthreads();
  int row = blockIdx.x * RPB + t / TPR;
  if (row >= n) return;
  int og = (t % TPR) * 16;
  float acc[16];
  #pragma unroll
  for (int j = 0; j < 16; ++j) acc[j] = 0.f;
  const float4* a4 = (const float4*)(A + (size_t)row * K);
  #pragma unroll 4
  for (int k4 = 0; k4 < K / 4; ++k4) {
    float4 xv = a4[k4];
    const float* wr = &sW[(k4 * 4) * OW + og];
    #pragma unroll
    for (int j = 0; j < 16; ++j) acc[j] += xv.x * wr[j];
    #pragma unroll
    for (int j = 0; j < 16; ++j) acc[j] += xv.y * wr[OW + j];
    #pragma unroll
    for (int j = 0; j < 16; ++j) acc[j] += xv.z * wr[2 * OW + j];
    #pragma unroll
    for (int j = 0; j < 16; ++j) acc[j] += xv.w * wr[3 * OW + j];
  }
  float sc = SCALE ? dis[row] : 1.f;
  float* o = out + (size_t)row * OW + og;
  #pragma unroll
  for (int j = 0; j < 16; ++j) {
    float v = acc[j];
    if (HAS_BIAS) v += bias[og + j];
    if (SCALE) v *= sc;
    if (LEAKY) v = v > 0.f ? v : ALPHA * v;
    o[j] = v;
  }
}

// ---------------- aggregation: wave per node ----------------

// conv1: 64 features, lane = feature. h1[d] = relu(dis[d]*(g[d] + sum g[s]) + b1)
__global__ __launch_bounds__(256) void k_agg1(const float* __restrict__ g,
    const float* __restrict__ dis, const float* __restrict__ bias,
    const int* __restrict__ rowptr, const int* __restrict__ lst,
    float* __restrict__ h, int n) {
  int wid = (blockIdx.x * 256 + threadIdx.x) >> 6;
  if (wid >= n) return;
  int lane = threadIdx.x & 63;
  float acc = g[(size_t)wid * 64 + lane];
  int j = rowptr[wid], end = rowptr[wid + 1];
  for (; j + 4 <= end; j += 4) {
    int s0 = lst[j], s1 = lst[j + 1], s2 = lst[j + 2], s3 = lst[j + 3];
    acc += g[(size_t)s0 * 64 + lane];
    acc += g[(size_t)s1 * 64 + lane];
    acc += g[(size_t)s2 * 64 + lane];
    acc += g[(size_t)s3 * 64 + lane];
  }
  for (; j < end; ++j) acc += g[(size_t)lst[j] * 64 + lane];
  float v = dis[wid] * acc + bias[lane];
  h[(size_t)wid * 64 + lane] = v > 0.f ? v : 0.f;
}

// conv2 + final linear: 32 features, two edges in parallel (lane = f + 32*half),
// then out[d] = relu(dis*(sum)+b2) . W3 + b3
__global__ __launch_bounds__(256) void k_agg2(const float* __restrict__ g,
    const float* __restrict__ dis, const float* __restrict__ bias,
    const float* __restrict__ W3, const float* __restrict__ b3,
    const int* __restrict__ rowptr, const int* __restrict__ lst,
    float* __restrict__ out, int n) {
  int wid = (blockIdx.x * 256 + threadIdx.x) >> 6;
  if (wid >= n) return;
  int lane = threadIdx.x & 63;
  int f = lane & 31, half = lane >> 5;
  float acc = (half == 0) ? g[(size_t)wid * 32 + f] : 0.f;  // self term once
  int beg = rowptr[wid], end = rowptr[wid + 1];
  for (int j = beg + half; j < end; j += 2)
    acc += g[(size_t)lst[j] * 32 + f];
  acc += __shfl_down(acc, 32);   // lanes 0..31 now hold full feature sums
  float res = 0.f;
  if (half == 0) {
    float v = dis[wid] * acc + bias[f];
    v = v > 0.f ? v : 0.f;
    res = v * W3[f];
  }
  res += __shfl_xor(res, 16);
  res += __shfl_xor(res, 8);
  res += __shfl_xor(res, 4);
  res += __shfl_xor(res, 2);
  res += __shfl_xor(res, 1);
  if (lane == 0) out[wid] = res + b3[0];
}

// ---------------- launch ----------------

extern "C" void kernel_launch(void* const* d_in, const int* in_sizes, int n_in,
                              void* d_out, int out_size, void* d_ws, size_t ws_size,
                              hipStream_t stream) {
  (void)n_in; (void)out_size; (void)ws_size;
  const float* x  = (const float*)d_in[0];
  const int*   ei = (const int*)d_in[2];
  const float* W0 = (const float*)d_in[3];
  const float* b0 = (const float*)d_in[4];
  const float* W1 = (const float*)d_in[5];
  const float* b1 = (const float*)d_in[6];
  const float* W2 = (const float*)d_in[7];
  const float* b2 = (const float*)d_in[8];
  const float* W3 = (const float*)d_in[9];
  const float* b3 = (const float*)d_in[10];
  float* out = (float*)d_out;
  int N = in_sizes[0] / NFEAT;
  int E = in_sizes[2] / 2;
  const int* src = ei;
  const int* dst = ei + E;

  char* ws = (char*)d_ws;
  size_t off = 0;
  auto alloc = [&](size_t bytes) -> char* {
    char* p = ws + off;
    off += (bytes + 255) & ~(size_t)255;
    return p;
  };
  int*   cnt  = (int*)alloc((size_t)N * 4);
  int*   fill = (int*)alloc((size_t)N * 4);
  int*   rowp = (int*)alloc((size_t)(N + 1) * 4);
  float* dis  = (float*)alloc((size_t)N * 4);
  int*   lst  = (int*)alloc((size_t)E * 4);
  float* bufA = (float*)alloc((size_t)N * 64 * 4);  // h0, then h1
  float* bufB = (float*)alloc((size_t)N * 64 * 4);  // g1, then g2

  int nb = (N + 255) / 256;
  int eb = (E + 255) / 256;
  k_zero2<<<nb, 256, 0, stream>>>(cnt, fill, N);
  k_hist<<<eb, 256, 0, stream>>>(dst, cnt, E);
  k_dis<<<nb, 256, 0, stream>>>(cnt, dis, N);
  k_scan<<<1, 1024, 0, stream>>>(cnt, rowp, N);
  k_fill<<<eb, 256, 0, stream>>>(src, dst, rowp, fill, lst, E);

  // h0 = leaky_relu(x@W0 + b0) -> bufA
  k_gemm<NFEAT, 64, true, true, false><<<(N + 63) / 64, 256, 0, stream>>>(x, W0, b0, nullptr, bufA, N);
  // g1 = (h0@W1)*dis -> bufB
  k_gemm<64, 64, false, false, true><<<(N + 63) / 64, 256, 0, stream>>>(bufA, W1, nullptr, dis, bufB, N);
  // h1 = relu(dis*(g1[d] + sum g1[s]) + b1) -> bufA
  k_agg1<<<(N + 3) / 4, 256, 0, stream>>>(bufB, dis, b1, rowp, lst, bufA, N);
  // g2 = (h1@W2)*dis -> bufB
  k_gemm<64, 32, false, false, true><<<(N + 127) / 128, 256, 0, stream>>>(bufA, W2, nullptr, dis, bufB, N);
  // out = relu(dis*(g2[d] + sum g2[s]) + b2) @ W3 + b3
  k_agg2<<<(N + 3) / 4, 256, 0, stream>>>(bufB, dis, b2, W3, b3, rowp, lst, out, N);
}

// Round 2
// 416.109 us; speedup vs baseline: 1.3013x; 1.3013x over previous
//
#include <hip/hip_runtime.h>
#include <hip/hip_bf16.h>

#define NFEAT 128
#define ALPHA 0.2f
#define SCAN_B 256   // blocks in multi-block scan (phase B scans exactly this many sums)

// ---------------- CSR build ----------------

__global__ __launch_bounds__(256) void k_zero2(int* __restrict__ a, int* __restrict__ b, int n) {
  int i = blockIdx.x * 256 + threadIdx.x;
  if (i < n) { a[i] = 0; b[i] = 0; }
}

__global__ __launch_bounds__(256) void k_hist(const int* __restrict__ dst, int* __restrict__ cnt, int E) {
  int e = blockIdx.x * 256 + threadIdx.x;
  if (e < E) atomicAdd(&cnt[dst[e]], 1);
}

__global__ __launch_bounds__(256) void k_dis(const int* __restrict__ cnt, float* __restrict__ dis, int n) {
  int i = blockIdx.x * 256 + threadIdx.x;
  if (i < n) dis[i] = rsqrtf((float)(cnt[i] + 1));  // +1 self-loop; deg>0 always
}

// ---- multi-block exclusive scan of cnt[0..n) -> rowptr[0..n] ----

// phase A: per-block sums
__global__ __launch_bounds__(256) void k_scanA(const int* __restrict__ cnt, int* __restrict__ bsum, int n) {
  __shared__ int ws[4];
  int b = blockIdx.x;
  int chunk = (n + SCAN_B - 1) / SCAN_B;
  int lo = b * chunk;
  int hi = lo + chunk; if (hi > n) hi = n;
  int s = 0;
  for (int i = lo + (int)threadIdx.x; i < hi; i += 256) s += cnt[i];
  #pragma unroll
  for (int o = 32; o; o >>= 1) s += __shfl_down(s, o);
  if ((threadIdx.x & 63) == 0) ws[threadIdx.x >> 6] = s;
  __syncthreads();
  if (threadIdx.x == 0) bsum[b] = ws[0] + ws[1] + ws[2] + ws[3];
}

// phase B: single block, exclusive scan of SCAN_B block sums (in place)
__global__ __launch_bounds__(SCAN_B) void k_scanB(int* __restrict__ bsum) {
  __shared__ int sh[SCAN_B];
  int t = threadIdx.x;
  int v = bsum[t];
  sh[t] = v;
  __syncthreads();
  for (int o = 1; o < SCAN_B; o <<= 1) {
    int u = (t >= o) ? sh[t - o] : 0;
    __syncthreads();
    sh[t] += u;
    __syncthreads();
  }
  bsum[t] = sh[t] - v;  // exclusive
}

// phase C: per-block exclusive prefix write
__global__ __launch_bounds__(256) void k_scanC(const int* __restrict__ cnt, const int* __restrict__ boff,
    int* __restrict__ rowptr, int n, int E) {
  __shared__ int sh[256];
  int b = blockIdx.x;
  int t = threadIdx.x;
  int chunk = (n + SCAN_B - 1) / SCAN_B;
  int lo = b * chunk;
  int hi = lo + chunk; if (hi > n) hi = n;
  int sub = (chunk + 255) >> 8;
  int tlo = lo + t * sub;
  int thi = tlo + sub; if (thi > hi) thi = hi;
  int s = 0;
  for (int i = tlo; i < thi; ++i) s += cnt[i];
  sh[t] = s;
  __syncthreads();
  int v = s;
  for (int o = 1; o < 256; o <<= 1) {
    int u = (t >= o) ? sh[t - o] : 0;
    __syncthreads();
    sh[t] += u;
    __syncthreads();
  }
  int run = boff[b] + sh[t] - v;
  for (int i = tlo; i < thi; ++i) { rowptr[i] = run; run += cnt[i]; }
  if (b == 0 && t == 0) rowptr[n] = E;
}

__global__ __launch_bounds__(256) void k_fill(const int* __restrict__ src, const int* __restrict__ dst,
    const int* __restrict__ rowptr, int* __restrict__ fill, int* __restrict__ lst, int E) {
  int e = blockIdx.x * 256 + threadIdx.x;
  if (e < E) {
    int d = dst[e];
    int p = rowptr[d] + atomicAdd(&fill[d], 1);
    lst[p] = src[e];
  }
}

// ---------------- skinny GEMMs (W in LDS, thread = 1 row x 16 outs) ----------------

template<int K, int OW, bool HAS_BIAS, bool LEAKY, bool SCALE>
__global__ __launch_bounds__(256) void k_gemm(const float* __restrict__ A,
    const float* __restrict__ W, const float* __restrict__ bias,
    const float* __restrict__ dis, float* __restrict__ out, int n) {
  constexpr int TPR = OW / 16;       // threads per row
  constexpr int RPB = 256 / TPR;     // rows per block
  __shared__ float sW[K * OW];
  int t = threadIdx.x;
  {
    constexpr int NV = (K * OW) / (4 * 256);
    const float4* W4 = (const float4*)W;
    float4* s4 = (float4*)sW;
    #pragma unroll
    for (int i = 0; i < NV; ++i) s4[t + i * 256] = W4[t + i * 256];
  }
  __syncthreads();
  int row = blockIdx.x * RPB + t / TPR;
  if (row >= n) return;
  int og = (t % TPR) * 16;
  float acc[16];
  #pragma unroll
  for (int j = 0; j < 16; ++j) acc[j] = 0.f;
  const float4* a4 = (const float4*)(A + (size_t)row * K);
  #pragma unroll 4
  for (int k4 = 0; k4 < K / 4; ++k4) {
    float4 xv = a4[k4];
    const float* wr = &sW[(k4 * 4) * OW + og];
    #pragma unroll
    for (int j = 0; j < 16; ++j) acc[j] += xv.x * wr[j];
    #pragma unroll
    for (int j = 0; j < 16; ++j) acc[j] += xv.y * wr[OW + j];
    #pragma unroll
    for (int j = 0; j < 16; ++j) acc[j] += xv.z * wr[2 * OW + j];
    #pragma unroll
    for (int j = 0; j < 16; ++j) acc[j] += xv.w * wr[3 * OW + j];
  }
  float sc = SCALE ? dis[row] : 1.f;
  float* o = out + (size_t)row * OW + og;
  #pragma unroll
  for (int j = 0; j < 16; ++j) {
    float v = acc[j];
    if (HAS_BIAS) v += bias[og + j];
    if (SCALE) v *= sc;
    if (LEAKY) v = v > 0.f ? v : ALPHA * v;
    o[j] = v;
  }
}

// ---------------- aggregation: wave per node ----------------

// conv1: 64 features, lane = feature. h1[d] = relu(dis[d]*(g[d] + sum g[s]) + b1)
__global__ __launch_bounds__(256) void k_agg1(const float* __restrict__ g,
    const float* __restrict__ dis, const float* __restrict__ bias,
    const int* __restrict__ rowptr, const int* __restrict__ lst,
    float* __restrict__ h, int n) {
  int wid = (blockIdx.x * 256 + threadIdx.x) >> 6;
  if (wid >= n) return;
  int lane = threadIdx.x & 63;
  float acc = g[(size_t)wid * 64 + lane];
  int j = rowptr[wid], end = rowptr[wid + 1];
  for (; j + 4 <= end; j += 4) {
    int s0 = lst[j], s1 = lst[j + 1], s2 = lst[j + 2], s3 = lst[j + 3];
    acc += g[(size_t)s0 * 64 + lane];
    acc += g[(size_t)s1 * 64 + lane];
    acc += g[(size_t)s2 * 64 + lane];
    acc += g[(size_t)s3 * 64 + lane];
  }
  for (; j < end; ++j) acc += g[(size_t)lst[j] * 64 + lane];
  float v = dis[wid] * acc + bias[lane];
  h[(size_t)wid * 64 + lane] = v > 0.f ? v : 0.f;
}

// conv2 + final linear: 32 features, two edges in parallel (lane = f + 32*half),
// then out[d] = relu(dis*(sum)+b2) . W3 + b3
__global__ __launch_bounds__(256) void k_agg2(const float* __restrict__ g,
    const float* __restrict__ dis, const float* __restrict__ bias,
    const float* __restrict__ W3, const float* __restrict__ b3,
    const int* __restrict__ rowptr, const int* __restrict__ lst,
    float* __restrict__ out, int n) {
  int wid = (blockIdx.x * 256 + threadIdx.x) >> 6;
  if (wid >= n) return;
  int lane = threadIdx.x & 63;
  int f = lane & 31, half = lane >> 5;
  float acc = (half == 0) ? g[(size_t)wid * 32 + f] : 0.f;  // self term once
  int beg = rowptr[wid], end = rowptr[wid + 1];
  for (int j = beg + half; j < end; j += 2)
    acc += g[(size_t)lst[j] * 32 + f];
  acc += __shfl_down(acc, 32);   // lanes 0..31 now hold full feature sums
  float res = 0.f;
  if (half == 0) {
    float v = dis[wid] * acc + bias[f];
    v = v > 0.f ? v : 0.f;
    res = v * W3[f];
  }
  res += __shfl_xor(res, 16);
  res += __shfl_xor(res, 8);
  res += __shfl_xor(res, 4);
  res += __shfl_xor(res, 2);
  res += __shfl_xor(res, 1);
  if (lane == 0) out[wid] = res + b3[0];
}

// ---------------- launch ----------------

extern "C" void kernel_launch(void* const* d_in, const int* in_sizes, int n_in,
                              void* d_out, int out_size, void* d_ws, size_t ws_size,
                              hipStream_t stream) {
  (void)n_in; (void)out_size; (void)ws_size;
  const float* x  = (const float*)d_in[0];
  const int*   ei = (const int*)d_in[2];
  const float* W0 = (const float*)d_in[3];
  const float* b0 = (const float*)d_in[4];
  const float* W1 = (const float*)d_in[5];
  const float* b1 = (const float*)d_in[6];
  const float* W2 = (const float*)d_in[7];
  const float* b2 = (const float*)d_in[8];
  const float* W3 = (const float*)d_in[9];
  const float* b3 = (const float*)d_in[10];
  float* out = (float*)d_out;
  int N = in_sizes[0] / NFEAT;
  int E = in_sizes[2] / 2;
  const int* src = ei;
  const int* dst = ei + E;

  char* ws = (char*)d_ws;
  size_t off = 0;
  auto alloc = [&](size_t bytes) -> char* {
    char* p = ws + off;
    off += (bytes + 255) & ~(size_t)255;
    return p;
  };
  int*   cnt  = (int*)alloc((size_t)N * 4);
  int*   fill = (int*)alloc((size_t)N * 4);
  int*   rowp = (int*)alloc((size_t)(N + 1) * 4);
  int*   bsum = (int*)alloc((size_t)SCAN_B * 4);
  float* dis  = (float*)alloc((size_t)N * 4);
  int*   lst  = (int*)alloc((size_t)E * 4);
  float* bufA = (float*)alloc((size_t)N * 64 * 4);  // h0, then h1
  float* bufB = (float*)alloc((size_t)N * 64 * 4);  // g1, then g2

  int nb = (N + 255) / 256;
  int eb = (E + 255) / 256;
  k_zero2<<<nb, 256, 0, stream>>>(cnt, fill, N);
  k_hist<<<eb, 256, 0, stream>>>(dst, cnt, E);
  k_dis<<<nb, 256, 0, stream>>>(cnt, dis, N);
  k_scanA<<<SCAN_B, 256, 0, stream>>>(cnt, bsum, N);
  k_scanB<<<1, SCAN_B, 0, stream>>>(bsum);
  k_scanC<<<SCAN_B, 256, 0, stream>>>(cnt, bsum, rowp, N, E);
  k_fill<<<eb, 256, 0, stream>>>(src, dst, rowp, fill, lst, E);

  // h0 = leaky_relu(x@W0 + b0) -> bufA
  k_gemm<NFEAT, 64, true, true, false><<<(N + 63) / 64, 256, 0, stream>>>(x, W0, b0, nullptr, bufA, N);
  // g1 = (h0@W1)*dis -> bufB
  k_gemm<64, 64, false, false, true><<<(N + 63) / 64, 256, 0, stream>>>(bufA, W1, nullptr, dis, bufB, N);
  // h1 = relu(dis*(g1[d] + sum g1[s]) + b1) -> bufA
  k_agg1<<<(N + 3) / 4, 256, 0, stream>>>(bufB, dis, b1, rowp, lst, bufA, N);
  // g2 = (h1@W2)*dis -> bufB
  k_gemm<64, 32, false, false, true><<<(N + 127) / 128, 256, 0, stream>>>(bufA, W2, nullptr, dis, bufB, N);
  // out = relu(dis*(g2[d] + sum g2[s]) + b2) @ W3 + b3
  k_agg2<<<(N + 3) / 4, 256, 0, stream>>>(bufB, dis, b2, W3, b3, rowp, lst, out, N);
}